// Round 2
// 259.386 us; speedup vs baseline: 1.1064x; 1.1064x over previous
//
#include <hip/hip_runtime.h>
#include <math.h>

#define B_    4
#define CIN_  128
#define COUT_ 128
#define H_    128
#define W_    128
#define HW_   (H_*W_)
#define KK_   9

typedef __attribute__((ext_vector_type(8))) short short8;
typedef __attribute__((ext_vector_type(4))) float f32x4;
typedef float f2v __attribute__((ext_vector_type(2), aligned(4)));  // 4B-aligned pair load

static __device__ __forceinline__ unsigned f2bf(float f) {
    union { float f; unsigned u; } v; v.f = f;
    return (v.u + 0x7fffu + ((v.u >> 16) & 1u)) >> 16;
}

// K-chunk order (both GEMMs): q = cblock*9 + tap (channel-outer, tap inner).

// ---------------------------------------------------------------------------
// Prep A: swizzle w_dc into MFMA A-fragment order, bf16 (unchanged).
// ---------------------------------------------------------------------------
__global__ __launch_bounds__(256) void wswz_kernel(
    const float* __restrict__ w_dc, unsigned short* __restrict__ w_swz)
{
    int idx = blockIdx.x * 256 + threadIdx.x;   // [0, 36*8*64)
    int q   = idx >> 9;
    int rem = idx & 511;
    int ocb = rem >> 6;
    int l   = rem & 63;
    int cbq = q / 9;
    int k   = q - cbq * 9;
    int cb  = (cbq << 5) + ((l >> 4) << 3);
    int oc  = (ocb << 4) + (l & 15);
    unsigned r[4];
#pragma unroll
    for (int j = 0; j < 4; ++j) {
        float f0 = w_dc[((size_t)(oc * CIN_ + cb + 2 * j    )) * KK_ + k];
        float f1 = w_dc[((size_t)(oc * CIN_ + cb + 2 * j + 1)) * KK_ + k];
        r[j] = f2bf(f0) | (f2bf(f1) << 16);
    }
    *(int4*)&w_swz[(size_t)idx * 8] = make_int4(r[0], r[1], r[2], r[3]);
}

// ---------------------------------------------------------------------------
// Prep B: swizzle w_off likewise, oc padded 27->32 (unchanged).
// ---------------------------------------------------------------------------
__global__ __launch_bounds__(256) void woffswz_kernel(
    const float* __restrict__ w_off, unsigned short* __restrict__ woff_swz)
{
    int idx = blockIdx.x * 256 + threadIdx.x;   // [0, 36*2*64)
    int q   = idx >> 7;
    int rem = idx & 127;
    int l   = rem & 63;
    int cbq = q / 9;
    int k   = q - cbq * 9;
    int cb  = (cbq << 5) + ((l >> 4) << 3);
    int oc  = ((rem >> 6) << 4) + (l & 15);
    unsigned r[4];
#pragma unroll
    for (int j = 0; j < 4; ++j) {
        float f0 = 0.f, f1 = 0.f;
        if (oc < 27) {
            f0 = w_off[((size_t)(oc * CIN_ + cb + 2 * j    )) * KK_ + k];
            f1 = w_off[((size_t)(oc * CIN_ + cb + 2 * j + 1)) * KK_ + k];
        }
        r[j] = f2bf(f0) | (f2bf(f1) << 16);
    }
    *(int4*)&woff_swz[(size_t)idx * 8] = make_int4(r[0], r[1], r[2], r[3]);
}

// ---------------------------------------------------------------------------
// Kernel 1 (v2): offset conv as LDS-tiled 3x3 conv. 64-px blocks (grid 1024,
// 4/CU). Per channel-block: stage [3 rows][66 px][32 ch] bf16 halo tile ONCE
// (coalesced f2v row loads), then 9 taps of ds_read_b128 + MFMA with A-frags
// register-prefetched 1 tap ahead. Barriers: 8/block (was 72).
// ---------------------------------------------------------------------------
__global__ __launch_bounds__(256, 4) void offset_mfma_kernel(
    const float* __restrict__ feat, const unsigned short* __restrict__ woff_swz,
    const float* __restrict__ b_off, float* __restrict__ offm)
{
    const int tid = threadIdx.x;
    const int bx = blockIdx.x;
    const int lidx = ((bx & 7) << 7) | (bx >> 3);   // XCD swizzle, 1024 blocks
    const int b  = lidx >> 8;
    const int h  = (lidx & 255) >> 1;
    const int w0 = (lidx & 1) << 6;

    // [row 0..2][tile-x 0..65][ch 0..31], px stride 40 shorts (16B-aligned b128 reads)
    __shared__ unsigned short s_F[3][66][40];

    const int lane = tid & 63;
    const int wave = tid >> 6;
    const int kg = lane >> 4, pn = lane & 15;

    const float* fbase = feat + (size_t)b * CIN_ * HW_;

    f32x4 acc[2];
    acc[0] = (f32x4){0.f, 0.f, 0.f, 0.f};
    acc[1] = (f32x4){0.f, 0.f, 0.f, 0.f};

    for (int cb = 0; cb < 4; ++cb) {
        if (cb) __syncthreads();           // taps of cb-1 done reading s_F

        // ---- stage halo tile for this 32-ch block ----
#pragma unroll
        for (int r = 0; r < 3; ++r) {
            const int y = h + r - 1;
            const bool yv = (unsigned)y < (unsigned)H_;   // block-uniform
            const float* rowp = fbase + (size_t)(cb << 5) * HW_ + y * W_;
            // main: 32 pair-slots (e 0..31) x 32 ch, lanes e-fast -> coalesced
#pragma unroll
            for (int j = 0; j < 4; ++j) {
                int item = tid + (j << 8);      // 0..1023
                int c = item >> 5;
                int e = item & 31;
                int x0 = w0 - 1 + 2 * e;
                int hx = min(max(x0, 0), W_ - 2);
                float v0 = 0.f, v1 = 0.f;
                if (yv) {
                    f2v p = *(const f2v*)(rowp + (size_t)c * HW_ + hx);
                    // x0==hx normal; x0==-1 -> (0, p.x); x0==W-1 -> (p.y, 0)
                    v0 = (x0 == hx) ? p.x : ((x0 < hx) ? 0.f : p.y);
                    v1 = (x0 == hx) ? p.y : ((x0 < hx) ? p.x : 0.f);
                }
                s_F[r][2 * e    ][c] = (unsigned short)f2bf(v0);
                s_F[r][2 * e + 1][c] = (unsigned short)f2bf(v1);
            }
            // tail pair e=32 (tile-x 64,65), 32 channel threads
            if (tid < 32) {
                int c = tid;
                int x0 = w0 + 63;
                int hx = min(x0, W_ - 2);
                float v0 = 0.f, v1 = 0.f;
                if (yv) {
                    f2v p = *(const f2v*)(rowp + (size_t)c * HW_ + hx);
                    v0 = (x0 == hx) ? p.x : p.y;    // x0>hx only when x0==W-1
                    v1 = (x0 == hx) ? p.y : 0.f;
                }
                s_F[r][64][c] = (unsigned short)f2bf(v0);
                s_F[r][65][c] = (unsigned short)f2bf(v1);
            }
        }
        __syncthreads();

        // ---- 9 taps, pure LDS + MFMA, A-frags prefetched 1 tap ahead ----
        const int qb2 = cb * 18;               // 2*(cb*9)
        const short8* wb = (const short8*)woff_swz;
        short8 a0 = wb[(size_t)(qb2    ) * 64 + lane];
        short8 a1 = wb[(size_t)(qb2 + 1) * 64 + lane];
#pragma unroll
        for (int k = 0; k < 9; ++k) {
            const int ky = k / 3, kx = k - 3 * ky;
            short8 bfr = *(const short8*)&s_F[ky][wave * 16 + pn + kx][kg * 8];
            short8 na0, na1;
            if (k < 8) {
                na0 = wb[(size_t)(qb2 + 2 * k + 2) * 64 + lane];
                na1 = wb[(size_t)(qb2 + 2 * k + 3) * 64 + lane];
            }
            acc[0] = __builtin_amdgcn_mfma_f32_16x16x32_bf16(a0, bfr, acc[0], 0, 0, 0);
            acc[1] = __builtin_amdgcn_mfma_f32_16x16x32_bf16(a1, bfr, acc[1], 0, 0, 0);
            if (k < 8) { a0 = na0; a1 = na1; }
        }
    }

    const int row0 = (lane >> 4) << 2;
    const int col  = lane & 15;
    const int pw   = w0 + wave * 16 + col;
#pragma unroll
    for (int mt = 0; mt < 2; ++mt) {
#pragma unroll
        for (int i = 0; i < 4; ++i) {
            int oc = mt * 16 + row0 + i;
            if (oc < 27) {
                float v = acc[mt][i] + b_off[oc];
                if (oc >= 18) v = 1.f / (1.f + __expf(-v));
                offm[((size_t)(b * 27 + oc)) * HW_ + h * W_ + pw] = v;
            }
        }
    }
}

// ---------------------------------------------------------------------------
// Kernel 2 (v2): modulated deformable conv. 64-px blocks (grid 1024, 4/CU),
// each thread builds 8 channels of 1 px (wider coalesced gathers, int4 LDS
// write). Double-buffered s_V -> ONE barrier per K-chunk (write buf[q&1],
// barrier, read buf[q&1]; next chunk writes the other buffer -> race-free).
// Gathers register-pipelined 1 chunk ahead; A-frags loaded pre-barrier.
// ---------------------------------------------------------------------------
__global__ __launch_bounds__(256, 4) void dcn_mfma_kernel(
    const float* __restrict__ inp, const float* __restrict__ offm,
    const unsigned short* __restrict__ w_swz, const float* __restrict__ b_dc,
    float* __restrict__ out)
{
    const int tid = threadIdx.x;
    const int bx = blockIdx.x;
    const int lidx = ((bx & 7) << 7) | (bx >> 3);   // XCD swizzle, 1024 blocks
    const int b   = lidx >> 8;
    const int h   = (lidx & 255) >> 1;
    const int pw0 = (lidx & 1) << 6;

    __shared__ int2   s_midx[576];        // [tap][px64]: top/bot pair base idx
    __shared__ float4 s_mwgt[576];        // pair weights (x-validity folded)
    __shared__ unsigned short s_V[2][64][40];   // double-buffered B tile

    // ---- bilinear pair metadata: 9 taps x 64 px ----
    for (int i = tid; i < 576; i += 256) {
        int k = i >> 6, p = i & 63;
        int ky = k / 3, kx = k - ky * 3;
        int pw = pw0 + p;
        const float* ob = offm + (size_t)b * 27 * HW_ + h * W_ + pw;
        float offy = ob[(2 * k    ) * HW_];
        float offx = ob[(2 * k + 1) * HW_];
        float mask = ob[(18 + k   ) * HW_];
        float py = offy + (float)(h  + ky - 1);
        float px_ = offx + (float)(pw + kx - 1);
        float y0f = floorf(py), x0f = floorf(px_);
        float ly = py - y0f, lx = px_ - x0f;
        int y0 = (int)y0f, x0 = (int)x0f;
        int y1 = y0 + 1;
        int hx = min(max(x0, 0), W_ - 2);
        float wlo = 0.f, whi = 0.f;
        if (x0 == hx)          { wlo = 1.f - lx; whi = lx; }     // normal
        else if (x0 == hx - 1) { wlo = lx; }                     // x0 == -1
        else if (x0 == hx + 1) { whi = 1.f - lx; }               // x0 == W-1
        float wt_top = ((unsigned)y0 < (unsigned)H_) ? (1.f - ly) * mask : 0.f;
        float wt_bot = ((unsigned)y1 < (unsigned)H_) ? ly * mask : 0.f;
        int cy0 = min(max(y0, 0), H_ - 1), cy1 = min(max(y1, 0), H_ - 1);
        s_midx[i] = make_int2(cy0 * W_ + hx, cy1 * W_ + hx);
        s_mwgt[i] = make_float4(wt_top * wlo, wt_top * whi,
                                wt_bot * wlo, wt_bot * whi);
    }

    const int lane = tid & 63;
    const int wave = tid >> 6;
    const int kg = lane >> 4, pn = lane & 15;
    const int px  = lane;                 // build pixel (tid & 63)
    const int cg8 = wave << 3;            // build channel base (0,8,16,24)

    const float* gbase = inp + (size_t)b * CIN_ * HW_;

    f32x4 acc[2][4];
#pragma unroll
    for (int mt = 0; mt < 2; ++mt)
#pragma unroll
        for (int nt = 0; nt < 4; ++nt) acc[mt][nt] = (f32x4){0.f, 0.f, 0.f, 0.f};

    f2v pf[16];  // [2j]=top pair, [2j+1]=bot pair, channel cg8+j (j=0..7)

    auto issue = [&](int qq) {
        int cbq = qq / 9;
        int k   = qq - cbq * 9;
        int2 id = s_midx[(k << 6) + px];
        const float* g = gbase + (size_t)((cbq << 5) + cg8) * HW_;
#pragma unroll
        for (int j = 0; j < 8; ++j) {
            pf[2 * j]     = *(const f2v*)(g + (size_t)j * HW_ + id.x);
            pf[2 * j + 1] = *(const f2v*)(g + (size_t)j * HW_ + id.y);
        }
    };

    __syncthreads();   // metadata visible
    issue(0);

    for (int q = 0; q < 36; ++q) {
        int k = q - (q / 9) * 9;

        // consume prefetched pairs
        float4 wt = s_mwgt[(k << 6) + px];
        float v[8];
#pragma unroll
        for (int j = 0; j < 8; ++j)
            v[j] = pf[2 * j].x * wt.x + pf[2 * j].y * wt.y
                 + pf[2 * j + 1].x * wt.z + pf[2 * j + 1].y * wt.w;
        unsigned r0 = f2bf(v[0]) | (f2bf(v[1]) << 16);
        unsigned r1 = f2bf(v[2]) | (f2bf(v[3]) << 16);
        unsigned r2 = f2bf(v[4]) | (f2bf(v[5]) << 16);
        unsigned r3 = f2bf(v[6]) | (f2bf(v[7]) << 16);
        *(int4*)&s_V[q & 1][px][cg8] = make_int4(r0, r1, r2, r3);

        int qn = (q + 1 < 36) ? q + 1 : 35;
        issue(qn);                         // gathers for next chunk in flight

        // A-fragments (L2-hot), consumed after the barrier
        const short8* wp = (const short8*)w_swz + (size_t)(q * 8 + wave * 2) * 64 + lane;
        short8 af0 = wp[0];
        short8 af1 = wp[64];

        __syncthreads();                   // buf[q&1] complete; prev reads done

#pragma unroll
        for (int nt = 0; nt < 4; ++nt) {
            short8 bfr = *(const short8*)&s_V[q & 1][nt * 16 + pn][kg * 8];
            acc[0][nt] = __builtin_amdgcn_mfma_f32_16x16x32_bf16(af0, bfr, acc[0][nt], 0, 0, 0);
            acc[1][nt] = __builtin_amdgcn_mfma_f32_16x16x32_bf16(af1, bfr, acc[1][nt], 0, 0, 0);
        }
    }

    const int row0 = (lane >> 4) << 2;
    const int col  = lane & 15;
#pragma unroll
    for (int mt = 0; mt < 2; ++mt) {
#pragma unroll
        for (int nt = 0; nt < 4; ++nt) {
            int pw = pw0 + nt * 16 + col;
#pragma unroll
            for (int i = 0; i < 4; ++i) {
                int oc = wave * 32 + mt * 16 + row0 + i;
                out[((size_t)(b * COUT_ + oc)) * HW_ + h * W_ + pw] =
                    acc[mt][nt][i] + b_dc[oc];
            }
        }
    }
}

extern "C" void kernel_launch(void* const* d_in, const int* in_sizes, int n_in,
                              void* d_out, int out_size, void* d_ws, size_t ws_size,
                              hipStream_t stream)
{
    const float* inp   = (const float*)d_in[0];
    const float* feat  = (const float*)d_in[1];
    const float* w_off = (const float*)d_in[2];
    const float* b_off = (const float*)d_in[3];
    const float* w_dc  = (const float*)d_in[4];
    const float* b_dc  = (const float*)d_in[5];
    float* out  = (float*)d_out;
    float* offm = (float*)d_ws;                                            // 7.08 MB
    unsigned short* w_swz    = (unsigned short*)((char*)d_ws + 7077888);           // 288 KB
    unsigned short* woff_swz = (unsigned short*)((char*)d_ws + 7077888 + 294912);  // 72 KB

    woffswz_kernel<<<dim3(18), dim3(256), 0, stream>>>(w_off, woff_swz);
    wswz_kernel<<<dim3(72), dim3(256), 0, stream>>>(w_dc, w_swz);
    offset_mfma_kernel<<<dim3(1024), dim3(256), 0, stream>>>(feat, woff_swz, b_off, offm);
    dcn_mfma_kernel<<<dim3(1024), dim3(256), 0, stream>>>(inp, offm, w_swz, b_dc, out);
}

// Round 4
// 186.695 us; speedup vs baseline: 1.5371x; 1.3894x over previous
//
#include <hip/hip_runtime.h>
#include <math.h>

#define B_    4
#define CIN_  128
#define COUT_ 128
#define H_    128
#define W_    128
#define HW_   (H_*W_)
#define KK_   9

typedef __attribute__((ext_vector_type(8))) short short8;
typedef __attribute__((ext_vector_type(4))) float f32x4;
typedef _Float16 h8 __attribute__((ext_vector_type(8)));
typedef float f2v __attribute__((ext_vector_type(2), aligned(4)));  // 4B-aligned pair load

static __device__ __forceinline__ unsigned f2bf(float f) {
    union { float f; unsigned u; } v; v.f = f;
    return (v.u + 0x7fffu + ((v.u >> 16) & 1u)) >> 16;
}
static __device__ __forceinline__ unsigned short f2h(float f) {
    union { _Float16 h; unsigned short u; } v; v.h = (_Float16)f;
    return v.u;
}

// K-chunk order (both GEMMs): q = cblock*9 + tap (channel-outer, tap inner).

// ---------------------------------------------------------------------------
// Prep 0: transpose inp [b][c][y][x] f32 -> inpT [b][y][x][c] f16.
// Block = (b,y); LDS tile [128x][142c] (stride 142 shorts: 2-way-max banks).
// ---------------------------------------------------------------------------
__global__ __launch_bounds__(256) void tpose_kernel(
    const float* __restrict__ inp, unsigned short* __restrict__ inpT)
{
    const int by = blockIdx.x;            // 0..511
    const int b = by >> 7, y = by & 127;
    __shared__ unsigned short s_T[128 * 142];   // 36352 B

    const float* src = inp + (size_t)b * CIN_ * HW_ + y * W_;
    const int xs = (threadIdx.x & 63) * 2;
    const int c0 = threadIdx.x >> 6;      // 0..3
#pragma unroll 4
    for (int p = 0; p < 32; ++p) {
        int c = c0 + 4 * p;
        f2v d = *(const f2v*)(src + (size_t)c * HW_ + xs);
        s_T[xs * 142 + c]       = f2h(d.x);
        s_T[(xs + 1) * 142 + c] = f2h(d.y);
    }
    __syncthreads();

    unsigned short* dst = inpT + (size_t)by * (W_ * CIN_);   // [x][c]
    const int cs = (threadIdx.x & 15) * 8;
    const int x0 = threadIdx.x >> 4;      // 16 x per pass
#pragma unroll
    for (int p = 0; p < 8; ++p) {
        int x = x0 + 16 * p;
        unsigned r[4];
#pragma unroll
        for (int j = 0; j < 4; ++j) {
            unsigned lo = s_T[x * 142 + cs + 2 * j];
            unsigned hi = s_T[x * 142 + cs + 2 * j + 1];
            r[j] = lo | (hi << 16);
        }
        *(int4*)(dst + (size_t)x * CIN_ + cs) = make_int4(r[0], r[1], r[2], r[3]);
    }
}

// ---------------------------------------------------------------------------
// Prep A: swizzle w_dc into MFMA A-fragment order, now f16 (for f16 MFMA).
// ---------------------------------------------------------------------------
__global__ __launch_bounds__(256) void wswz_kernel(
    const float* __restrict__ w_dc, unsigned short* __restrict__ w_swz)
{
    int idx = blockIdx.x * 256 + threadIdx.x;   // [0, 36*8*64)
    int q   = idx >> 9;
    int rem = idx & 511;
    int ocb = rem >> 6;
    int l   = rem & 63;
    int cbq = q / 9;
    int k   = q - cbq * 9;
    int cb  = (cbq << 5) + ((l >> 4) << 3);
    int oc  = (ocb << 4) + (l & 15);
    unsigned r[4];
#pragma unroll
    for (int j = 0; j < 4; ++j) {
        float f0 = w_dc[((size_t)(oc * CIN_ + cb + 2 * j    )) * KK_ + k];
        float f1 = w_dc[((size_t)(oc * CIN_ + cb + 2 * j + 1)) * KK_ + k];
        r[j] = (unsigned)f2h(f0) | ((unsigned)f2h(f1) << 16);
    }
    *(int4*)&w_swz[(size_t)idx * 8] = make_int4(r[0], r[1], r[2], r[3]);
}

// ---------------------------------------------------------------------------
// Prep B: swizzle w_off likewise, oc padded 27->32, bf16 (offset kernel).
// ---------------------------------------------------------------------------
__global__ __launch_bounds__(256) void woffswz_kernel(
    const float* __restrict__ w_off, unsigned short* __restrict__ woff_swz)
{
    int idx = blockIdx.x * 256 + threadIdx.x;   // [0, 36*2*64)
    int q   = idx >> 7;
    int rem = idx & 127;
    int l   = rem & 63;
    int cbq = q / 9;
    int k   = q - cbq * 9;
    int cb  = (cbq << 5) + ((l >> 4) << 3);
    int oc  = ((rem >> 6) << 4) + (l & 15);
    unsigned r[4];
#pragma unroll
    for (int j = 0; j < 4; ++j) {
        float f0 = 0.f, f1 = 0.f;
        if (oc < 27) {
            f0 = w_off[((size_t)(oc * CIN_ + cb + 2 * j    )) * KK_ + k];
            f1 = w_off[((size_t)(oc * CIN_ + cb + 2 * j + 1)) * KK_ + k];
        }
        r[j] = f2bf(f0) | (f2bf(f1) << 16);
    }
    *(int4*)&woff_swz[(size_t)idx * 8] = make_int4(r[0], r[1], r[2], r[3]);
}

// ---------------------------------------------------------------------------
// Kernel 1: offset conv as LDS-tiled 3x3 conv (unchanged from v2, 28.9 us).
// ---------------------------------------------------------------------------
__global__ __launch_bounds__(256, 4) void offset_mfma_kernel(
    const float* __restrict__ feat, const unsigned short* __restrict__ woff_swz,
    const float* __restrict__ b_off, float* __restrict__ offm)
{
    const int tid = threadIdx.x;
    const int bx = blockIdx.x;
    const int lidx = ((bx & 7) << 7) | (bx >> 3);   // XCD swizzle, 1024 blocks
    const int b  = lidx >> 8;
    const int h  = (lidx & 255) >> 1;
    const int w0 = (lidx & 1) << 6;

    __shared__ unsigned short s_F[3][66][40];

    const int lane = tid & 63;
    const int wave = tid >> 6;
    const int kg = lane >> 4, pn = lane & 15;

    const float* fbase = feat + (size_t)b * CIN_ * HW_;

    f32x4 acc[2];
    acc[0] = (f32x4){0.f, 0.f, 0.f, 0.f};
    acc[1] = (f32x4){0.f, 0.f, 0.f, 0.f};

    for (int cb = 0; cb < 4; ++cb) {
        if (cb) __syncthreads();

#pragma unroll
        for (int r = 0; r < 3; ++r) {
            const int y = h + r - 1;
            const bool yv = (unsigned)y < (unsigned)H_;
            const float* rowp = fbase + (size_t)(cb << 5) * HW_ + y * W_;
#pragma unroll
            for (int j = 0; j < 4; ++j) {
                int item = tid + (j << 8);
                int c = item >> 5;
                int e = item & 31;
                int x0 = w0 - 1 + 2 * e;
                int hx = min(max(x0, 0), W_ - 2);
                float v0 = 0.f, v1 = 0.f;
                if (yv) {
                    f2v p = *(const f2v*)(rowp + (size_t)c * HW_ + hx);
                    v0 = (x0 == hx) ? p.x : ((x0 < hx) ? 0.f : p.y);
                    v1 = (x0 == hx) ? p.y : ((x0 < hx) ? p.x : 0.f);
                }
                s_F[r][2 * e    ][c] = (unsigned short)f2bf(v0);
                s_F[r][2 * e + 1][c] = (unsigned short)f2bf(v1);
            }
            if (tid < 32) {
                int c = tid;
                int x0 = w0 + 63;
                int hx = min(x0, W_ - 2);
                float v0 = 0.f, v1 = 0.f;
                if (yv) {
                    f2v p = *(const f2v*)(rowp + (size_t)c * HW_ + hx);
                    v0 = (x0 == hx) ? p.x : p.y;
                    v1 = (x0 == hx) ? p.y : 0.f;
                }
                s_F[r][64][c] = (unsigned short)f2bf(v0);
                s_F[r][65][c] = (unsigned short)f2bf(v1);
            }
        }
        __syncthreads();

        const int qb2 = cb * 18;
        const short8* wb = (const short8*)woff_swz;
        short8 a0 = wb[(size_t)(qb2    ) * 64 + lane];
        short8 a1 = wb[(size_t)(qb2 + 1) * 64 + lane];
#pragma unroll
        for (int k = 0; k < 9; ++k) {
            const int ky = k / 3, kx = k - 3 * ky;
            short8 bfr = *(const short8*)&s_F[ky][wave * 16 + pn + kx][kg * 8];
            short8 na0, na1;
            if (k < 8) {
                na0 = wb[(size_t)(qb2 + 2 * k + 2) * 64 + lane];
                na1 = wb[(size_t)(qb2 + 2 * k + 3) * 64 + lane];
            }
            acc[0] = __builtin_amdgcn_mfma_f32_16x16x32_bf16(a0, bfr, acc[0], 0, 0, 0);
            acc[1] = __builtin_amdgcn_mfma_f32_16x16x32_bf16(a1, bfr, acc[1], 0, 0, 0);
            if (k < 8) { a0 = na0; a1 = na1; }
        }
    }

    const int row0 = (lane >> 4) << 2;
    const int col  = lane & 15;
    const int pw   = w0 + wave * 16 + col;
#pragma unroll
    for (int mt = 0; mt < 2; ++mt) {
#pragma unroll
        for (int i = 0; i < 4; ++i) {
            int oc = mt * 16 + row0 + i;
            if (oc < 27) {
                float v = acc[mt][i] + b_off[oc];
                if (oc >= 18) v = 1.f / (1.f + __expf(-v));
                offm[((size_t)(b * 27 + oc)) * HW_ + h * W_ + pw] = v;
            }
        }
    }
}

// ---------------------------------------------------------------------------
// Kernel 2 (v3): modulated deformable conv, f16 channel-last gathers.
// Per chunk each thread (px = t>>2, cs = t&3) loads its 4 bilinear corners
// as 4x dwordx4 (8 f16 ch each, full-line use; 4 lanes/corner => 16 lines
// per wave instr). Packed-f16 bilinear combine -> s_V f16 -> f16 MFMA.
// A-frags issued BEFORE gathers so MFMA's vmcnt wait leaves them in flight.
// ---------------------------------------------------------------------------
__global__ __launch_bounds__(256, 4) void dcn_mfma_kernel(
    const unsigned short* __restrict__ inpT, const float* __restrict__ offm,
    const unsigned short* __restrict__ w_swz, const float* __restrict__ b_dc,
    float* __restrict__ out)
{
    const int tid = threadIdx.x;
    const int bx = blockIdx.x;
    const int lidx = ((bx & 7) << 7) | (bx >> 3);   // XCD swizzle, 1024 blocks
    const int b   = lidx >> 8;
    const int h   = (lidx & 255) >> 1;
    const int pw0 = (lidx & 1) << 6;

    __shared__ int2   s_midx[576];        // [tap][px64]: (top,bot) row base idx
    __shared__ float4 s_mwgt[576];        // 4 corner weights (validity folded)
    __shared__ unsigned short s_V[2][64][40];   // double-buffered B tile (f16)

    // ---- bilinear corner metadata: 9 taps x 64 px ----
    for (int i = tid; i < 576; i += 256) {
        int k = i >> 6, p = i & 63;
        int ky = k / 3, kx = k - ky * 3;
        int pw = pw0 + p;
        const float* ob = offm + (size_t)b * 27 * HW_ + h * W_ + pw;
        float offy = ob[(2 * k    ) * HW_];
        float offx = ob[(2 * k + 1) * HW_];
        float mask = ob[(18 + k   ) * HW_];
        float py = offy + (float)(h  + ky - 1);
        float px_ = offx + (float)(pw + kx - 1);
        float y0f = floorf(py), x0f = floorf(px_);
        float ly = py - y0f, lx = px_ - x0f;
        int y0 = (int)y0f, x0 = (int)x0f;
        int y1 = y0 + 1;
        int hx = min(max(x0, 0), W_ - 2);
        float wlo = 0.f, whi = 0.f;
        if (x0 == hx)          { wlo = 1.f - lx; whi = lx; }     // normal
        else if (x0 == hx - 1) { wlo = lx; }                     // x0 == -1
        else if (x0 == hx + 1) { whi = 1.f - lx; }               // x0 == W-1
        float wt_top = ((unsigned)y0 < (unsigned)H_) ? (1.f - ly) * mask : 0.f;
        float wt_bot = ((unsigned)y1 < (unsigned)H_) ? ly * mask : 0.f;
        int cy0 = min(max(y0, 0), H_ - 1), cy1 = min(max(y1, 0), H_ - 1);
        s_midx[i] = make_int2(cy0 * W_ + hx, cy1 * W_ + hx);
        s_mwgt[i] = make_float4(wt_top * wlo, wt_top * whi,
                                wt_bot * wlo, wt_bot * whi);
    }

    const int lane = tid & 63;
    const int wave = tid >> 6;
    const int kg = lane >> 4, pn = lane & 15;
    const int px = tid >> 2;              // gather pixel 0..63
    const int cs = tid & 3;               // channel quarter (8 ch)

    const char* inpTb = (const char*)(inpT + (size_t)b * CIN_ * HW_);

    f32x4 acc[2][4];
#pragma unroll
    for (int mt = 0; mt < 2; ++mt)
#pragma unroll
        for (int nt = 0; nt < 4; ++nt) acc[mt][nt] = (f32x4){0.f, 0.f, 0.f, 0.f};

    h8 pf0, pf1, pf2, pf3;   // corners: (y0,x0),(y0,x1),(y1,x0),(y1,x1)

    auto issue = [&](int qq) {
        int cbq = qq / 9;
        int k   = qq - cbq * 9;
        int2 id = s_midx[(k << 6) + px];
        int coff = (cbq << 6) + (cs << 4);
        const char* g0 = inpTb + ((size_t)(unsigned)id.x << 8) + coff;
        const char* g1 = inpTb + ((size_t)(unsigned)id.y << 8) + coff;
        pf0 = *(const h8*)(g0);
        pf1 = *(const h8*)(g0 + 256);     // x+1: +CIN_*2B
        pf2 = *(const h8*)(g1);
        pf3 = *(const h8*)(g1 + 256);
    };

    __syncthreads();   // metadata visible
    issue(0);

    for (int q = 0; q < 36; ++q) {
        int k = q - (q / 9) * 9;

        // consume prefetched corners: packed-f16 bilinear (v_pk ops)
        float4 wt = s_mwgt[(k << 6) + px];
        h8 v = pf0 * (_Float16)wt.x;
        v += pf1 * (_Float16)wt.y;
        v += pf2 * (_Float16)wt.z;
        v += pf3 * (_Float16)wt.w;

        // A-fragments FIRST (so MFMA's vmcnt wait keeps gathers in flight)
        const h8* wp = (const h8*)w_swz + (size_t)(q * 8 + wave * 2) * 64 + lane;
        h8 af0 = wp[0];
        h8 af1 = wp[64];

        *(h8*)&s_V[q & 1][px][cs << 3] = v;

        int qn = (q + 1 < 36) ? q + 1 : 35;
        issue(qn);                         // gathers for next chunk in flight

        __syncthreads();                   // buf[q&1] complete; prev reads done

#pragma unroll
        for (int nt = 0; nt < 4; ++nt) {
            h8 bfr = *(const h8*)&s_V[q & 1][nt * 16 + pn][kg * 8];
            acc[0][nt] = __builtin_amdgcn_mfma_f32_16x16x32_f16(af0, bfr, acc[0][nt], 0, 0, 0);
            acc[1][nt] = __builtin_amdgcn_mfma_f32_16x16x32_f16(af1, bfr, acc[1][nt], 0, 0, 0);
        }
    }

    const int row0 = (lane >> 4) << 2;
    const int col  = lane & 15;
#pragma unroll
    for (int mt = 0; mt < 2; ++mt) {
#pragma unroll
        for (int nt = 0; nt < 4; ++nt) {
            int pw = pw0 + nt * 16 + col;
#pragma unroll
            for (int i = 0; i < 4; ++i) {
                int oc = wave * 32 + mt * 16 + row0 + i;
                out[((size_t)(b * COUT_ + oc)) * HW_ + h * W_ + pw] =
                    acc[mt][nt][i] + b_dc[oc];
            }
        }
    }
}

extern "C" void kernel_launch(void* const* d_in, const int* in_sizes, int n_in,
                              void* d_out, int out_size, void* d_ws, size_t ws_size,
                              hipStream_t stream)
{
    const float* inp   = (const float*)d_in[0];
    const float* feat  = (const float*)d_in[1];
    const float* w_off = (const float*)d_in[2];
    const float* b_off = (const float*)d_in[3];
    const float* w_dc  = (const float*)d_in[4];
    const float* b_dc  = (const float*)d_in[5];
    float* out  = (float*)d_out;
    float* offm = (float*)d_ws;                                                    // 7.08 MB
    unsigned short* w_swz    = (unsigned short*)((char*)d_ws + 7077888);           // 288 KB (f16)
    unsigned short* woff_swz = (unsigned short*)((char*)d_ws + 7077888 + 294912);  // 72 KB (bf16)
    unsigned short* inpT     = (unsigned short*)((char*)d_ws + 7446528);           // 16 MB (f16 NHWC)

    tpose_kernel<<<dim3(512), dim3(256), 0, stream>>>(inp, inpT);
    woffswz_kernel<<<dim3(18), dim3(256), 0, stream>>>(w_off, woff_swz);
    wswz_kernel<<<dim3(72), dim3(256), 0, stream>>>(w_dc, w_swz);
    offset_mfma_kernel<<<dim3(1024), dim3(256), 0, stream>>>(feat, woff_swz, b_off, offm);
    dcn_mfma_kernel<<<dim3(1024), dim3(256), 0, stream>>>(inpT, offm, w_swz, b_dc, out);
}